// Round 3
// baseline (1803.826 us; speedup 1.0000x reference)
//
#include <hip/hip_runtime.h>

#define N_NODES 50000
#define N_EDGES 800000
#define NLAYERS 4
#define NTILES (N_EDGES / 64)

#define W1P 232      // padded W1 pitch (bf16 elems), global AND LDS layout
#define TPITCH 72
#define AGPITCH 72
#define SCHUNK 49    // 1024 * 49 = 50176 >= N_NODES
#define EDGE_GRID 768

typedef short bf16x8 __attribute__((ext_vector_type(8)));
typedef float f32x4 __attribute__((ext_vector_type(4)));

__device__ __forceinline__ unsigned short f2b(float f) {
  union { float f; unsigned int u; } v; v.f = f;
  unsigned int u = v.u;
  return (unsigned short)((u + 0x7fffu + ((u >> 16) & 1u)) >> 16);
}
__device__ __forceinline__ float b2f(unsigned short s) {
  union { unsigned int u; float f; } v; v.u = ((unsigned int)s) << 16;
  return v.f;
}
__device__ __forceinline__ unsigned int pack2(float lo, float hi) {
  return (unsigned int)f2b(lo) | ((unsigned int)f2b(hi) << 16);
}
__device__ __forceinline__ float silu_f(float x) {
  return x / (1.0f + __expf(-x));
}

// ---------------- CSR build + edge sort (once; edge_index layer-invariant) ----------------
__global__ void k_hist(const int* __restrict__ eidx, int* __restrict__ cnt) {
  int e = blockIdx.x * 256 + threadIdx.x;
  if (e >= N_EDGES) return;
  atomicAdd(&cnt[eidx[e]], 1);
}
__global__ __launch_bounds__(1024) void k_scan(const int* __restrict__ cnt,
                                               int* __restrict__ rowptr,
                                               int* __restrict__ cur) {
  __shared__ int part[1024];
  const int t = threadIdx.x;
  const int base = t * SCHUNK;
  int s = 0;
  for (int i = 0; i < SCHUNK; i++) {
    int idx = base + i;
    s += (idx < N_NODES) ? cnt[idx] : 0;
  }
  part[t] = s;
  __syncthreads();
  for (int off = 1; off < 1024; off <<= 1) {
    int v = (t >= off) ? part[t - off] : 0;
    __syncthreads();
    part[t] += v;
    __syncthreads();
  }
  int run = (t == 0) ? 0 : part[t - 1];
  for (int i = 0; i < SCHUNK; i++) {
    int idx = base + i;
    if (idx < N_NODES) {
      rowptr[idx] = run;
      cur[idx] = run;
      run += cnt[idx];
    }
  }
  if (t == 1023) rowptr[N_NODES] = part[1023];
}
// scatter edges into row-sorted order; build perm tables + sorted r/c/mask
__global__ void k_scatter(const int* __restrict__ eidx, const float* __restrict__ emask,
                          int* __restrict__ cur, int* __restrict__ elist,
                          int* __restrict__ einv, int* __restrict__ rs,
                          int* __restrict__ cs, float* __restrict__ msrt) {
  int e = blockIdx.x * 256 + threadIdx.x;
  if (e >= N_EDGES) return;
  int r = eidx[e], c = eidx[N_EDGES + e];
  int slot = atomicAdd(&cur[r], 1);
  elist[slot] = e;
  einv[e] = slot;
  rs[slot] = r;
  cs[slot] = c;
  msrt[slot] = emask[e];
}

// ---------------- weight conversion ----------------
// eW1 [L,193,64] -> Wt1 [L,64,W1P] bf16, transposed + k-permuted + padded:
// new k: 0..63 h_row, 64..127 h_col, 128..191 e, 192 radial, 193..231 zero
__global__ void k_convW1(const float* __restrict__ eW1, unsigned short* __restrict__ Wt1) {
  int id = blockIdx.x * 256 + threadIdx.x;
  if (id >= NLAYERS * 64 * W1P) return;
  int k = id % W1P; int rem = id / W1P; int o = rem % 64; int l = rem / 64;
  int src = (k < 128) ? k : (k < 192 ? k + 1 : (k == 192 ? 128 : -1));
  float v = (src >= 0) ? eW1[((size_t)l * 193 + src) * 64 + o] : 0.0f;
  Wt1[id] = f2b(v);
}
// W [L,K,64] -> Wt [L,64,K] bf16
__global__ void k_convT(const float* __restrict__ W, unsigned short* __restrict__ Wt, int K) {
  int id = blockIdx.x * 256 + threadIdx.x;
  if (id >= NLAYERS * 64 * K) return;
  int k = id % K; int rem = id / K; int o = rem % 64; int l = rem / 64;
  Wt[id] = f2b(W[((size_t)l * K + k) * 64 + o]);
}

// ---------------- embeddings ----------------
__global__ void k_h0(const float* __restrict__ hin, const float* __restrict__ W,
                     const float* __restrict__ b, float* __restrict__ h,
                     unsigned short* __restrict__ hbf) {
  int id = blockIdx.x * 256 + threadIdx.x;
  if (id >= N_NODES * 64) return;
  int n = id >> 6, j = id & 63;
  float s = b[j];
#pragma unroll
  for (int k = 0; k < 16; k++) s += hin[n * 16 + k] * W[k * 64 + j];
  h[id] = s;
  hbf[id] = f2b(s);
}
// writes ebuf in SORTED edge order: ebuf[pos] = embed(edge_attr[elist[pos]])
__global__ void k_e0(const float* __restrict__ ea, const float* __restrict__ W,
                     const float* __restrict__ b, const int* __restrict__ elist,
                     unsigned short* __restrict__ ebuf) {
  int id = blockIdx.x * 256 + threadIdx.x;
  if (id >= N_EDGES * 64) return;
  int pos = id >> 6, j = id & 63;
  int e = elist[pos];
  float s = b[j];
#pragma unroll
  for (int k = 0; k < 8; k++) s += ea[e * 8 + k] * W[k * 64 + j];
  ebuf[id] = f2b(s);
}

// ---------------- fused edge kernel (one layer) ----------------
// Persistent blocks; W1 staged in LDS once; GEMM2/3 B in VGPRs; edges processed
// in row-sorted order (hbf[r] gathers coalesce; ebuf rows sequential).
__global__ __launch_bounds__(256, 3) void edge_kernel(
    const unsigned short* __restrict__ hbf, unsigned short* __restrict__ ebuf,
    const float* __restrict__ xin, float* __restrict__ xout,
    const int* __restrict__ rs, const int* __restrict__ cs,
    const float* __restrict__ msrt,
    const unsigned short* __restrict__ Wt1,
    const unsigned short* __restrict__ Wt2,
    const unsigned short* __restrict__ Wtc,
    const float* __restrict__ eb1, const float* __restrict__ eb2,
    const float* __restrict__ cb1, const float* __restrict__ cw2) {
  __shared__ __attribute__((aligned(16))) unsigned short sW1[64 * W1P];
  __shared__ __attribute__((aligned(16))) unsigned short sT[64 * TPITCH];
  __shared__ __attribute__((aligned(16))) unsigned short sM[64 * TPITCH];
  __shared__ float sNdx[64 * 3];
  __shared__ float sMaskS[64];
  __shared__ int sRow[64];

  const int t = threadIdx.x;
  const int lane = t & 63, w = t >> 6;
  const int q = lane >> 4, li = lane & 15;
  const int erow = w * 16 + li;

  // stage W1 (identical linear layout, coalesced full lines)
  for (int i = t; i < 64 * W1P / 8; i += 256)
    ((uint4*)sW1)[i] = ((const uint4*)Wt1)[i];

  // per-lane register B-fragments for GEMM2 / GEMM3 (loaded once)
  bf16x8 w2f[2][4], wcf[2][4];
#pragma unroll
  for (int ks = 0; ks < 2; ks++)
#pragma unroll
    for (int ct = 0; ct < 4; ct++) {
      w2f[ks][ct] = *(const bf16x8*)(Wt2 + (size_t)(ct * 16 + li) * 64 + ks * 32 + q * 8);
      wcf[ks][ct] = *(const bf16x8*)(Wtc + (size_t)(ct * 16 + li) * 64 + ks * 32 + q * 8);
    }
  // layer-constant biases/weights (hoisted out of tile loop)
  float b1v[4], b2v[4], cb1v[4], cw2v[4];
#pragma unroll
  for (int ct = 0; ct < 4; ct++) {
    b1v[ct] = eb1[ct * 16 + li];
    b2v[ct] = eb2[ct * 16 + li];
    cb1v[ct] = cb1[ct * 16 + li];
    cw2v[ct] = cw2[ct * 16 + li];
  }
  __syncthreads();

  const f32x4 zero4 = {0.f, 0.f, 0.f, 0.f};

  for (int tile = blockIdx.x; tile < NTILES; tile += gridDim.x) {
    const int e = tile * 64 + erow;
    const int r = rs[e], c = cs[e];

    // ebuf rows for this tile are sequential (sorted storage)
    const unsigned short* ep = ebuf + (size_t)e * 64;
    bf16x8 af4 = *(const bf16x8*)(ep + q * 8);
    bf16x8 af5 = *(const bf16x8*)(ep + 32 + q * 8);

    float dx0 = xin[r * 3 + 0] - xin[c * 3 + 0];
    float dx1 = xin[r * 3 + 1] - xin[c * 3 + 1];
    float dx2 = xin[r * 3 + 2] - xin[c * 3 + 2];
    float rad = dx0 * dx0 + dx1 * dx1 + dx2 * dx2;
    if (q == 0) {
      float inv = 1.0f / (sqrtf(rad) + 1.0f);
      sRow[erow] = r;
      sMaskS[erow] = msrt[e];
      sNdx[erow * 3 + 0] = dx0 * inv;
      sNdx[erow * 3 + 1] = dx1 * inv;
      sNdx[erow * 3 + 2] = dx2 * inv;
    }

    const unsigned short* hr = hbf + (size_t)r * 64;
    const unsigned short* hc = hbf + (size_t)c * 64;

    f32x4 acc[4];
#pragma unroll
    for (int ct = 0; ct < 4; ct++) acc[ct] = zero4;

    // GEMM1: K = [h_row(64) | h_col(64) | e(64) | radial | pad], B from LDS
    {
      bf16x8 afs[7];
      afs[0] = *(const bf16x8*)(hr + q * 8);
      afs[1] = *(const bf16x8*)(hr + 32 + q * 8);
      afs[2] = *(const bf16x8*)(hc + q * 8);
      afs[3] = *(const bf16x8*)(hc + 32 + q * 8);
      afs[4] = af4;
      afs[5] = af5;
      bf16x8 a6 = {0, 0, 0, 0, 0, 0, 0, 0};
      if (q == 0) a6[0] = (short)f2b(rad);
      afs[6] = a6;
#pragma unroll
      for (int ks = 0; ks < 7; ks++) {
        int kb = ks * 32 + q * 8;
#pragma unroll
        for (int ct = 0; ct < 4; ct++) {
          bf16x8 bfr = *(const bf16x8*)(sW1 + (ct * 16 + li) * W1P + kb);
          acc[ct] = __builtin_amdgcn_mfma_f32_16x16x32_bf16(afs[ks], bfr, acc[ct], 0, 0, 0);
        }
      }
    }
#pragma unroll
    for (int ct = 0; ct < 4; ct++) {
#pragma unroll
      for (int r2 = 0; r2 < 4; r2++) {
        int el = w * 16 + q * 4 + r2;
        sT[el * TPITCH + ct * 16 + li] = f2b(silu_f(acc[ct][r2] + b1v[ct]));
      }
    }
    // wave-private sT — no barrier

    // GEMM2 -> m (B from VGPR)
#pragma unroll
    for (int ct = 0; ct < 4; ct++) acc[ct] = zero4;
#pragma unroll
    for (int ks = 0; ks < 2; ks++) {
      int kb = ks * 32 + q * 8;
      bf16x8 af = *(const bf16x8*)(sT + erow * TPITCH + kb);
#pragma unroll
      for (int ct = 0; ct < 4; ct++)
        acc[ct] = __builtin_amdgcn_mfma_f32_16x16x32_bf16(af, w2f[ks][ct], acc[ct], 0, 0, 0);
    }
#pragma unroll
    for (int ct = 0; ct < 4; ct++) {
#pragma unroll
      for (int r2 = 0; r2 < 4; r2++) {
        int el = w * 16 + q * 4 + r2;
        float v = silu_f(acc[ct][r2] + b2v[ct]) * sMaskS[el];
        sM[el * TPITCH + ct * 16 + li] = f2b(v);
      }
    }

    // write m back to ebuf (sorted rows, contiguous; wave-private rows)
    {
      int el2 = t >> 2, part = t & 3;
      const uint4* src = (const uint4*)(sM + el2 * TPITCH + part * 16);
      uint4* dst = (uint4*)(ebuf + (size_t)(tile * 64 + el2) * 64 + part * 16);
      dst[0] = src[0]; dst[1] = src[1];
    }

    // GEMM3: u = silu(m@cW1+cb1), p = u . cw2 (B from VGPR)
#pragma unroll
    for (int ct = 0; ct < 4; ct++) acc[ct] = zero4;
#pragma unroll
    for (int ks = 0; ks < 2; ks++) {
      int kb = ks * 32 + q * 8;
      bf16x8 af = *(const bf16x8*)(sM + erow * TPITCH + kb);
#pragma unroll
      for (int ct = 0; ct < 4; ct++)
        acc[ct] = __builtin_amdgcn_mfma_f32_16x16x32_bf16(af, wcf[ks][ct], acc[ct], 0, 0, 0);
    }
    float p[4] = {0.f, 0.f, 0.f, 0.f};
#pragma unroll
    for (int ct = 0; ct < 4; ct++) {
#pragma unroll
      for (int r2 = 0; r2 < 4; r2++) p[r2] += silu_f(acc[ct][r2] + cb1v[ct]) * cw2v[ct];
    }
#pragma unroll
    for (int m = 1; m < 16; m <<= 1) {
#pragma unroll
      for (int r2 = 0; r2 < 4; r2++) p[r2] += __shfl_xor(p[r2], m, 64);
    }
    if (li < 3) {
#pragma unroll
      for (int r2 = 0; r2 < 4; r2++) {
        int el = w * 16 + q * 4 + r2;
        atomicAdd(&xout[(size_t)sRow[el] * 3 + li], sNdx[el * 3 + li] * p[r2]);
      }
    }
  }
}

// ---------------- node kernel (one layer) ----------------
// Sorted ebuf -> aggregation is SEQUENTIAL streaming over rowptr[n]..rowptr[n+1].
// B-matrices in per-lane VGPR fragments.
__global__ __launch_bounds__(256, 3) void node_kernel(
    float* __restrict__ h, unsigned short* __restrict__ hbf,
    const unsigned short* __restrict__ ebuf,
    float* __restrict__ xout, const float* __restrict__ nmask,
    const int* __restrict__ rowptr,
    const unsigned short* __restrict__ Wtn1,
    const unsigned short* __restrict__ Wtn2,
    const float* __restrict__ nb1, const float* __restrict__ nb2) {
  __shared__ __attribute__((aligned(16))) unsigned short sAgg[64 * AGPITCH];
  __shared__ __attribute__((aligned(16))) unsigned short sT[64 * TPITCH];
  const int t = threadIdx.x;
  const int nb = blockIdx.x * 64;
  const int lane = t & 63, w = t >> 6;
  const int q = lane >> 4, li = lane & 15;

  // per-lane B fragments (issue early; latency hides under aggregation)
  bf16x8 wn1f[4][4], wn2f[2][4];
#pragma unroll
  for (int ks = 0; ks < 4; ks++)
#pragma unroll
    for (int ct = 0; ct < 4; ct++)
      wn1f[ks][ct] = *(const bf16x8*)(Wtn1 + (size_t)(ct * 16 + li) * 128 + ks * 32 + q * 8);
#pragma unroll
  for (int ks = 0; ks < 2; ks++)
#pragma unroll
    for (int ct = 0; ct < 4; ct++)
      wn2f[ks][ct] = *(const bf16x8*)(Wtn2 + (size_t)(ct * 16 + li) * 64 + ks * 32 + q * 8);

  if (t < 192) {
    int n2 = nb + t / 3, c2 = t % 3;
    if (n2 < N_NODES) xout[(size_t)n2 * 3 + c2] *= nmask[n2];
  }

  // sequential CSR aggregation: 4 lanes per node, 16 channels per lane (f32)
  {
    int sub = lane >> 2;            // 0..15
    int part = lane & 3;            // 0..3
    int nl = w * 16 + sub;          // block-local node 0..63
    int node = nb + nl;
    float a16[16];
#pragma unroll
    for (int i = 0; i < 16; i++) a16[i] = 0.f;
    if (node < N_NODES) {
      int beg = rowptr[node], end = rowptr[node + 1];
      for (int ii = beg; ii < end; ii++) {
        const unsigned short* mp = ebuf + (size_t)ii * 64 + part * 16;
        bf16x8 v0 = *(const bf16x8*)(mp);
        bf16x8 v1 = *(const bf16x8*)(mp + 8);
#pragma unroll
        for (int j = 0; j < 8; j++) {
          a16[j]     += b2f((unsigned short)v0[j]);
          a16[8 + j] += b2f((unsigned short)v1[j]);
        }
      }
    }
    unsigned int* dst = (unsigned int*)(sAgg + nl * AGPITCH + part * 16);
#pragma unroll
    for (int i = 0; i < 8; i++) dst[i] = pack2(a16[2 * i], a16[2 * i + 1]);
  }
  // wave-private sAgg — no barrier

  const int nrow = w * 16 + li;
  const int n = nb + nrow;
  const bool valid = (n < N_NODES);
  const f32x4 zero4 = {0.f, 0.f, 0.f, 0.f};

  f32x4 acc[4];
#pragma unroll
  for (int ct = 0; ct < 4; ct++) acc[ct] = zero4;

  // A = [h(64) | agg(64)]
  {
    bf16x8 afs[4];
    const bf16x8 az = {0, 0, 0, 0, 0, 0, 0, 0};
    if (valid) {
      afs[0] = *(const bf16x8*)(hbf + (size_t)n * 64 + q * 8);
      afs[1] = *(const bf16x8*)(hbf + (size_t)n * 64 + 32 + q * 8);
    } else {
      afs[0] = az; afs[1] = az;
    }
    afs[2] = *(const bf16x8*)(sAgg + nrow * AGPITCH + q * 8);
    afs[3] = *(const bf16x8*)(sAgg + nrow * AGPITCH + 32 + q * 8);
#pragma unroll
    for (int ks = 0; ks < 4; ks++) {
#pragma unroll
      for (int ct = 0; ct < 4; ct++)
        acc[ct] = __builtin_amdgcn_mfma_f32_16x16x32_bf16(afs[ks], wn1f[ks][ct], acc[ct], 0, 0, 0);
    }
  }
#pragma unroll
  for (int ct = 0; ct < 4; ct++) {
    float bias = nb1[ct * 16 + li];
#pragma unroll
    for (int r2 = 0; r2 < 4; r2++) {
      int nl = w * 16 + q * 4 + r2;
      sT[nl * TPITCH + ct * 16 + li] = f2b(silu_f(acc[ct][r2] + bias));
    }
  }
  // wave-private sT — no barrier

#pragma unroll
  for (int ct = 0; ct < 4; ct++) acc[ct] = zero4;
#pragma unroll
  for (int ks = 0; ks < 2; ks++) {
    int kb = ks * 32 + q * 8;
    bf16x8 af = *(const bf16x8*)(sT + nrow * TPITCH + kb);
#pragma unroll
    for (int ct = 0; ct < 4; ct++)
      acc[ct] = __builtin_amdgcn_mfma_f32_16x16x32_bf16(af, wn2f[ks][ct], acc[ct], 0, 0, 0);
  }
#pragma unroll
  for (int ct = 0; ct < 4; ct++) {
    float bias = nb2[ct * 16 + li];
#pragma unroll
    for (int r2 = 0; r2 < 4; r2++) {
      int node = nb + w * 16 + q * 4 + r2;
      if (node < N_NODES) {
        float nm = nmask[node];
        size_t o = (size_t)node * 64 + ct * 16 + li;
        float hv = (h[o] + acc[ct][r2] + bias) * nm;
        h[o] = hv;
        hbf[o] = f2b(hv);
      }
    }
  }
}

// ---------------- output heads ----------------
__global__ void k_hout(const float* __restrict__ h, const float* __restrict__ W,
                       const float* __restrict__ b, const float* __restrict__ nmask,
                       float* __restrict__ out) {
  int id = blockIdx.x * 256 + threadIdx.x;
  if (id >= N_NODES * 16) return;
  int n = id >> 4, j = id & 15;
  float s = b[j];
#pragma unroll
  for (int k = 0; k < 64; k++) s += h[(size_t)n * 64 + k] * W[k * 16 + j];
  out[id] = s * nmask[n];
}
// ebuf is in sorted order -> un-permute via einv
__global__ void k_eout(const unsigned short* __restrict__ ebuf, const float* __restrict__ W,
                       const float* __restrict__ b, const float* __restrict__ emask,
                       const int* __restrict__ einv, float* __restrict__ out) {
  int id = blockIdx.x * 256 + threadIdx.x;
  if (id >= N_EDGES * 8) return;
  int e = id >> 3, j = id & 7;
  int pos = einv[e];
  float s = b[j];
#pragma unroll
  for (int k = 0; k < 64; k++) s += b2f(ebuf[(size_t)pos * 64 + k]) * W[k * 8 + j];
  out[id] = s * emask[e];
}

extern "C" void kernel_launch(void* const* d_in, const int* in_sizes, int n_in,
                              void* d_out, int out_size, void* d_ws, size_t ws_size,
                              hipStream_t stream) {
  (void)in_sizes; (void)n_in; (void)out_size; (void)ws_size;
  const float* in_h   = (const float*)d_in[0];
  const float* in_x   = (const float*)d_in[1];
  const float* in_ea  = (const float*)d_in[2];
  const float* nmask  = (const float*)d_in[3];
  const float* emask  = (const float*)d_in[4];
  const float* Wn_in  = (const float*)d_in[5];
  const float* bn_in  = (const float*)d_in[6];
  const float* Wn_out = (const float*)d_in[7];
  const float* bn_out = (const float*)d_in[8];
  const float* We_in  = (const float*)d_in[9];
  const float* be_in  = (const float*)d_in[10];
  const float* We_out = (const float*)d_in[11];
  const float* be_out = (const float*)d_in[12];
  const float* eW1    = (const float*)d_in[13];
  const float* eb1    = (const float*)d_in[14];
  const float* eW2    = (const float*)d_in[15];
  const float* eb2    = (const float*)d_in[16];
  const float* nW1    = (const float*)d_in[17];
  const float* nb1    = (const float*)d_in[18];
  const float* nW2    = (const float*)d_in[19];
  const float* nb2    = (const float*)d_in[20];
  const float* cW1    = (const float*)d_in[21];
  const float* cb1    = (const float*)d_in[22];
  const float* cW2    = (const float*)d_in[23];
  const int*   eidx   = (const int*)d_in[24];

  char* ws = (char*)d_ws;
  size_t off = 0;
  auto alloc = [&](size_t bytes) {
    size_t o = off; off = (off + bytes + 255) & ~(size_t)255; return (void*)(ws + o);
  };
  float* h             = (float*)alloc((size_t)N_NODES * 64 * 4);
  unsigned short* hbf  = (unsigned short*)alloc((size_t)N_NODES * 64 * 2);
  unsigned short* ebuf = (unsigned short*)alloc((size_t)N_EDGES * 64 * 2);
  float* xb0           = (float*)alloc((size_t)N_NODES * 3 * 4);
  float* xb1           = (float*)alloc((size_t)N_NODES * 3 * 4);
  int* cnt             = (int*)alloc((size_t)N_NODES * 4);
  int* rowptr          = (int*)alloc((size_t)(N_NODES + 1) * 4);
  int* cur             = (int*)alloc((size_t)N_NODES * 4);
  int* elist           = (int*)alloc((size_t)N_EDGES * 4);
  int* einv            = (int*)alloc((size_t)N_EDGES * 4);
  int* rsorted         = (int*)alloc((size_t)N_EDGES * 4);
  int* csorted         = (int*)alloc((size_t)N_EDGES * 4);
  float* msorted       = (float*)alloc((size_t)N_EDGES * 4);
  unsigned short* Wt1  = (unsigned short*)alloc((size_t)NLAYERS * 64 * W1P * 2);
  unsigned short* Wt2  = (unsigned short*)alloc((size_t)NLAYERS * 64 * 64 * 2);
  unsigned short* Wtc  = (unsigned short*)alloc((size_t)NLAYERS * 64 * 64 * 2);
  unsigned short* Wtn1 = (unsigned short*)alloc((size_t)NLAYERS * 64 * 128 * 2);
  unsigned short* Wtn2 = (unsigned short*)alloc((size_t)NLAYERS * 64 * 64 * 2);

  // one-time CSR build + edge sort (edge_index constant across layers)
  hipMemsetAsync(cnt, 0, (size_t)N_NODES * 4, stream);
  k_hist<<<(N_EDGES + 255) / 256, 256, 0, stream>>>(eidx, cnt);
  k_scan<<<1, 1024, 0, stream>>>(cnt, rowptr, cur);
  k_scatter<<<(N_EDGES + 255) / 256, 256, 0, stream>>>(eidx, emask, cur, elist, einv,
                                                       rsorted, csorted, msorted);

  k_convW1<<<(NLAYERS * 64 * W1P + 255) / 256, 256, 0, stream>>>(eW1, Wt1);
  k_convT<<<(NLAYERS * 64 * 64 + 255) / 256, 256, 0, stream>>>(eW2, Wt2, 64);
  k_convT<<<(NLAYERS * 64 * 64 + 255) / 256, 256, 0, stream>>>(cW1, Wtc, 64);
  k_convT<<<(NLAYERS * 64 * 128 + 255) / 256, 256, 0, stream>>>(nW1, Wtn1, 128);
  k_convT<<<(NLAYERS * 64 * 64 + 255) / 256, 256, 0, stream>>>(nW2, Wtn2, 64);

  k_h0<<<(N_NODES * 64 + 255) / 256, 256, 0, stream>>>(in_h, Wn_in, bn_in, h, hbf);
  k_e0<<<(N_EDGES * 64 + 255) / 256, 256, 0, stream>>>(in_ea, We_in, be_in, elist, ebuf);
  hipMemcpyAsync(xb0, in_x, (size_t)N_NODES * 3 * 4, hipMemcpyDeviceToDevice, stream);

  for (int l = 0; l < NLAYERS; l++) {
    float* xi = (l & 1) ? xb1 : xb0;
    float* xo = (l & 1) ? xb0 : xb1;
    hipMemcpyAsync(xo, xi, (size_t)N_NODES * 3 * 4, hipMemcpyDeviceToDevice, stream);
    edge_kernel<<<EDGE_GRID, 256, 0, stream>>>(
        hbf, ebuf, xi, xo, rsorted, csorted, msorted,
        Wt1 + (size_t)l * 64 * W1P, Wt2 + (size_t)l * 64 * 64, Wtc + (size_t)l * 64 * 64,
        eb1 + l * 64, eb2 + l * 64, cb1 + l * 64, cW2 + l * 64);
    node_kernel<<<(N_NODES + 63) / 64, 256, 0, stream>>>(
        h, hbf, ebuf, xo, nmask, rowptr,
        Wtn1 + (size_t)l * 64 * 128, Wtn2 + (size_t)l * 64 * 64, nb1 + l * 64, nb2 + l * 64);
  }

  float* out = (float*)d_out;
  k_hout<<<(N_NODES * 16 + 255) / 256, 256, 0, stream>>>(h, Wn_out, bn_out, nmask, out);
  k_eout<<<(N_EDGES * 8 + 255) / 256, 256, 0, stream>>>(ebuf, We_out, be_out, emask, einv,
                                                        out + 950000);
  hipMemcpyAsync(out + 800000, xb0, (size_t)N_NODES * 3 * 4, hipMemcpyDeviceToDevice, stream);
}

// Round 4
// 1599.999 us; speedup vs baseline: 1.1274x; 1.1274x over previous
//
#include <hip/hip_runtime.h>

#define N_NODES 50000
#define N_EDGES 800000
#define NLAYERS 4
#define NTILES (N_EDGES / 64)

#define K1PAD 224
#define TPITCH 72
#define SCHUNK 49    // 1024 * 49 = 50176 >= N_NODES

typedef short bf16x8 __attribute__((ext_vector_type(8)));
typedef float f32x4 __attribute__((ext_vector_type(4)));

__device__ __forceinline__ unsigned short f2b(float f) {
  union { float f; unsigned int u; } v; v.f = f;
  unsigned int u = v.u;
  return (unsigned short)((u + 0x7fffu + ((u >> 16) & 1u)) >> 16);
}
__device__ __forceinline__ float b2f(unsigned short s) {
  union { unsigned int u; float f; } v; v.u = ((unsigned int)s) << 16;
  return v.f;
}
__device__ __forceinline__ float silu_f(float x) {
  return x / (1.0f + __expf(-x));
}

// ---------------- CSR build + edge sort (once; edge_index layer-invariant) ----------------
__global__ void k_hist(const int* __restrict__ eidx, int* __restrict__ cnt) {
  int e = blockIdx.x * 256 + threadIdx.x;
  if (e >= N_EDGES) return;
  atomicAdd(&cnt[eidx[e]], 1);
}
__global__ __launch_bounds__(1024) void k_scan(const int* __restrict__ cnt,
                                               int* __restrict__ rowptr,
                                               int* __restrict__ cur) {
  __shared__ int part[1024];
  const int t = threadIdx.x;
  const int base = t * SCHUNK;
  int s = 0;
  for (int i = 0; i < SCHUNK; i++) {
    int idx = base + i;
    s += (idx < N_NODES) ? cnt[idx] : 0;
  }
  part[t] = s;
  __syncthreads();
  for (int off = 1; off < 1024; off <<= 1) {
    int v = (t >= off) ? part[t - off] : 0;
    __syncthreads();
    part[t] += v;
    __syncthreads();
  }
  int run = (t == 0) ? 0 : part[t - 1];
  for (int i = 0; i < SCHUNK; i++) {
    int idx = base + i;
    if (idx < N_NODES) {
      rowptr[idx] = run;
      cur[idx] = run;
      run += cnt[idx];
    }
  }
  if (t == 1023) rowptr[N_NODES] = part[1023];
}
// scatter edges into row-sorted order; sorted r/c/mask + perm table
__global__ void k_scatter(const int* __restrict__ eidx, const float* __restrict__ emask,
                          int* __restrict__ cur, int* __restrict__ elist,
                          int* __restrict__ rs, int* __restrict__ cs,
                          float* __restrict__ msrt) {
  int e = blockIdx.x * 256 + threadIdx.x;
  if (e >= N_EDGES) return;
  int r = eidx[e], c = eidx[N_EDGES + e];
  int slot = atomicAdd(&cur[r], 1);
  elist[slot] = e;
  rs[slot] = r;
  cs[slot] = c;
  msrt[slot] = emask[e];
}

// ---------------- weight conversion ----------------
// eW1 [L,193,64] -> Wt1 [L,64,224] bf16, transposed + k-permuted:
// new k: 0..63 h_row, 64..127 h_col, 128..191 e, 192 radial, 193.. zero
__global__ void k_convW1(const float* __restrict__ eW1, unsigned short* __restrict__ Wt1) {
  int id = blockIdx.x * 256 + threadIdx.x;
  if (id >= NLAYERS * 64 * K1PAD) return;
  int k = id % K1PAD; int rem = id / K1PAD; int o = rem % 64; int l = rem / 64;
  int src = (k < 128) ? k : (k < 192 ? k + 1 : (k == 192 ? 128 : -1));
  float v = (src >= 0) ? eW1[((size_t)l * 193 + src) * 64 + o] : 0.0f;
  Wt1[id] = f2b(v);
}
// W [L,K,64] -> Wt [L,64,K] bf16
__global__ void k_convT(const float* __restrict__ W, unsigned short* __restrict__ Wt, int K) {
  int id = blockIdx.x * 256 + threadIdx.x;
  if (id >= NLAYERS * 64 * K) return;
  int k = id % K; int rem = id / K; int o = rem % 64; int l = rem / 64;
  Wt[id] = f2b(W[((size_t)l * K + k) * 64 + o]);
}

// ---------------- embeddings ----------------
__global__ void k_h0(const float* __restrict__ hin, const float* __restrict__ W,
                     const float* __restrict__ b, float* __restrict__ h,
                     unsigned short* __restrict__ hbf) {
  int id = blockIdx.x * 256 + threadIdx.x;
  if (id >= N_NODES * 64) return;
  int n = id >> 6, j = id & 63;
  float s = b[j];
#pragma unroll
  for (int k = 0; k < 16; k++) s += hin[n * 16 + k] * W[k * 64 + j];
  h[id] = s;
  hbf[id] = f2b(s);
}
// writes ebuf in SORTED edge order: ebuf[pos] = embed(edge_attr[elist[pos]])
__global__ void k_e0(const float* __restrict__ ea, const float* __restrict__ W,
                     const float* __restrict__ b, const int* __restrict__ elist,
                     unsigned short* __restrict__ ebuf) {
  int id = blockIdx.x * 256 + threadIdx.x;
  if (id >= N_EDGES * 64) return;
  int pos = id >> 6, j = id & 63;
  int e = elist[pos];
  float s = b[j];
#pragma unroll
  for (int k = 0; k < 8; k++) s += ea[e * 8 + k] * W[k * 64 + j];
  ebuf[id] = f2b(s);
}

// ---------------- fused edge kernel (one layer) ----------------
// Barrier-free, wave-private, row-sorted edges. Aggregation fused here as a
// wave-private segmented reduce (sorted rows -> ~2 atomic flushes per wave).
__global__ __launch_bounds__(256) void edge_kernel(
    const unsigned short* __restrict__ hbf, unsigned short* __restrict__ ebuf,
    const float* __restrict__ xin, float* __restrict__ xout,
    float* __restrict__ agg,
    const int* __restrict__ rs, const int* __restrict__ cs,
    const float* __restrict__ msrt,
    const unsigned short* __restrict__ Wt1,
    const unsigned short* __restrict__ Wt2,
    const unsigned short* __restrict__ Wtc,
    const float* __restrict__ eb1, const float* __restrict__ eb2,
    const float* __restrict__ cb1, const float* __restrict__ cw2) {
  __shared__ __attribute__((aligned(16))) unsigned short sT[64 * TPITCH];
  __shared__ __attribute__((aligned(16))) unsigned short sM[64 * TPITCH];
  __shared__ float sNdx[64 * 3];
  __shared__ float sMaskS[64];
  __shared__ int sRow[64];

  const int t = threadIdx.x;
  const int lane = t & 63, w = t >> 6;
  const int q = lane >> 4, li = lane & 15;
  const int erow = w * 16 + li;
  const int e = blockIdx.x * 64 + erow;

  const int r = rs[e], c = cs[e];

  // only q==0 lanes need the coordinate gathers (radial + ndx + scalars)
  float rad = 0.f;
  if (q == 0) {
    float dx0 = xin[r * 3 + 0] - xin[c * 3 + 0];
    float dx1 = xin[r * 3 + 1] - xin[c * 3 + 1];
    float dx2 = xin[r * 3 + 2] - xin[c * 3 + 2];
    rad = dx0 * dx0 + dx1 * dx1 + dx2 * dx2;
    float inv = 1.0f / (sqrtf(rad) + 1.0f);
    sRow[erow] = r;
    sMaskS[erow] = msrt[e];
    sNdx[erow * 3 + 0] = dx0 * inv;
    sNdx[erow * 3 + 1] = dx1 * inv;
    sNdx[erow * 3 + 2] = dx2 * inv;
  }

  const unsigned short* hr = hbf + (size_t)r * 64;
  const unsigned short* hc = hbf + (size_t)c * 64;
  const unsigned short* ep = ebuf + (size_t)e * 64;

  f32x4 acc[4];
  const f32x4 zero4 = {0.f, 0.f, 0.f, 0.f};
#pragma unroll
  for (int ct = 0; ct < 4; ct++) acc[ct] = zero4;

  // GEMM1: K = [h_row(64) | h_col(64) | e(64) | radial | pad]
  {
    bf16x8 afs[7];
    afs[0] = *(const bf16x8*)(hr + q * 8);
    afs[1] = *(const bf16x8*)(hr + 32 + q * 8);
    afs[2] = *(const bf16x8*)(hc + q * 8);
    afs[3] = *(const bf16x8*)(hc + 32 + q * 8);
    afs[4] = *(const bf16x8*)(ep + q * 8);
    afs[5] = *(const bf16x8*)(ep + 32 + q * 8);
    bf16x8 a6 = {0, 0, 0, 0, 0, 0, 0, 0};
    if (q == 0) a6[0] = (short)f2b(rad);
    afs[6] = a6;
#pragma unroll
    for (int ks = 0; ks < 7; ks++) {
      int kb = ks * 32 + q * 8;
#pragma unroll
      for (int ct = 0; ct < 4; ct++) {
        bf16x8 bfr = *(const bf16x8*)(Wt1 + (size_t)(ct * 16 + li) * K1PAD + kb);
        acc[ct] = __builtin_amdgcn_mfma_f32_16x16x32_bf16(afs[ks], bfr, acc[ct], 0, 0, 0);
      }
    }
  }
#pragma unroll
  for (int ct = 0; ct < 4; ct++) {
    float bias = eb1[ct * 16 + li];
#pragma unroll
    for (int r2 = 0; r2 < 4; r2++) {
      int el = w * 16 + q * 4 + r2;
      sT[el * TPITCH + ct * 16 + li] = f2b(silu_f(acc[ct][r2] + bias));
    }
  }
  // wave-private sT — no barrier

  // GEMM2 -> m
#pragma unroll
  for (int ct = 0; ct < 4; ct++) acc[ct] = zero4;
#pragma unroll
  for (int ks = 0; ks < 2; ks++) {
    int kb = ks * 32 + q * 8;
    bf16x8 af = *(const bf16x8*)(sT + erow * TPITCH + kb);
#pragma unroll
    for (int ct = 0; ct < 4; ct++) {
      bf16x8 bfr = *(const bf16x8*)(Wt2 + (size_t)(ct * 16 + li) * 64 + kb);
      acc[ct] = __builtin_amdgcn_mfma_f32_16x16x32_bf16(af, bfr, acc[ct], 0, 0, 0);
    }
  }
#pragma unroll
  for (int ct = 0; ct < 4; ct++) {
    float bias = eb2[ct * 16 + li];
#pragma unroll
    for (int r2 = 0; r2 < 4; r2++) {
      int el = w * 16 + q * 4 + r2;
      float v = silu_f(acc[ct][r2] + bias) * sMaskS[el];
      sM[el * TPITCH + ct * 16 + li] = f2b(v);
    }
  }

  // write m back to ebuf (sorted rows, contiguous; wave-private rows)
  {
    int el2 = t >> 2, part = t & 3;
    const uint4* src = (const uint4*)(sM + el2 * TPITCH + part * 16);
    uint4* dst = (uint4*)(ebuf + (size_t)(blockIdx.x * 64 + el2) * 64 + part * 16);
    dst[0] = src[0]; dst[1] = src[1];
  }

  // fused aggregation: wave-private segmented reduce over this wave's 16
  // sorted edges (lane = channel). Rows sorted -> run-length merge, ~2 atomics.
  {
    float accv = 0.f;
    int curRow = sRow[w * 16];
#pragma unroll
    for (int i = 0; i < 16; i++) {
      int rr = sRow[w * 16 + i];
      float v = b2f(sM[(w * 16 + i) * TPITCH + lane]);
      if (rr != curRow) {   // wave-uniform branch
        atomicAdd(&agg[(size_t)curRow * 64 + lane], accv);
        accv = 0.f;
        curRow = rr;
      }
      accv += v;
    }
    atomicAdd(&agg[(size_t)curRow * 64 + lane], accv);
  }

  // GEMM3: u = silu(m@cW1+cb1), p = u . cw2
#pragma unroll
  for (int ct = 0; ct < 4; ct++) acc[ct] = zero4;
#pragma unroll
  for (int ks = 0; ks < 2; ks++) {
    int kb = ks * 32 + q * 8;
    bf16x8 af = *(const bf16x8*)(sM + erow * TPITCH + kb);
#pragma unroll
    for (int ct = 0; ct < 4; ct++) {
      bf16x8 bfr = *(const bf16x8*)(Wtc + (size_t)(ct * 16 + li) * 64 + kb);
      acc[ct] = __builtin_amdgcn_mfma_f32_16x16x32_bf16(af, bfr, acc[ct], 0, 0, 0);
    }
  }
  float p[4] = {0.f, 0.f, 0.f, 0.f};
#pragma unroll
  for (int ct = 0; ct < 4; ct++) {
    float bias = cb1[ct * 16 + li];
    float wv = cw2[ct * 16 + li];
#pragma unroll
    for (int r2 = 0; r2 < 4; r2++) p[r2] += silu_f(acc[ct][r2] + bias) * wv;
  }
#pragma unroll
  for (int m = 1; m < 16; m <<= 1) {
#pragma unroll
    for (int r2 = 0; r2 < 4; r2++) p[r2] += __shfl_xor(p[r2], m, 64);
  }
  // xout scatter with in-lane run merging (4 consecutive sorted edges per lane)
  if (li < 3) {
    int el0 = w * 16 + q * 4;
    float accx = sNdx[el0 * 3 + li] * p[0];
    int cr = sRow[el0];
#pragma unroll
    for (int r2 = 1; r2 < 4; r2++) {
      int el = el0 + r2;
      int rr = sRow[el];
      float tv = sNdx[el * 3 + li] * p[r2];
      if (rr != cr) {
        atomicAdd(&xout[(size_t)cr * 3 + li], accx);
        accx = 0.f;
        cr = rr;
      }
      accx += tv;
    }
    atomicAdd(&xout[(size_t)cr * 3 + li], accx);
  }
}

// ---------------- node kernel (one layer) ----------------
// Pure streaming: agg precomputed (f32) by edge kernel; no gather loop.
__global__ __launch_bounds__(256) void node_kernel(
    float* __restrict__ h, unsigned short* __restrict__ hbf,
    const float* __restrict__ agg,
    float* __restrict__ xout, const float* __restrict__ nmask,
    const unsigned short* __restrict__ Wtn1,
    const unsigned short* __restrict__ Wtn2,
    const float* __restrict__ nb1, const float* __restrict__ nb2) {
  __shared__ __attribute__((aligned(16))) unsigned short sT[64 * TPITCH];
  const int t = threadIdx.x;
  const int nb = blockIdx.x * 64;

  if (t < 192) {
    int n2 = nb + t / 3, c2 = t % 3;
    if (n2 < N_NODES) xout[(size_t)n2 * 3 + c2] *= nmask[n2];
  }

  const int lane = t & 63, w = t >> 6;
  const int q = lane >> 4, li = lane & 15;
  const int nrow = w * 16 + li;
  const int n = nb + nrow;
  const bool valid = (n < N_NODES);
  const f32x4 zero4 = {0.f, 0.f, 0.f, 0.f};

  f32x4 acc[4];
#pragma unroll
  for (int ct = 0; ct < 4; ct++) acc[ct] = zero4;

  // A = [h(64) | agg(64)]; h direct bf16, agg f32 -> bf16 in-register
  {
    bf16x8 afs[4];
    const bf16x8 az = {0, 0, 0, 0, 0, 0, 0, 0};
    if (valid) {
      afs[0] = *(const bf16x8*)(hbf + (size_t)n * 64 + q * 8);
      afs[1] = *(const bf16x8*)(hbf + (size_t)n * 64 + 32 + q * 8);
      const float* ap = agg + (size_t)n * 64;
      bf16x8 a2, a3;
#pragma unroll
      for (int j = 0; j < 8; j++) {
        a2[j] = (short)f2b(ap[q * 8 + j]);
        a3[j] = (short)f2b(ap[32 + q * 8 + j]);
      }
      afs[2] = a2; afs[3] = a3;
    } else {
      afs[0] = az; afs[1] = az; afs[2] = az; afs[3] = az;
    }
#pragma unroll
    for (int ks = 0; ks < 4; ks++) {
      int kb = ks * 32 + q * 8;
#pragma unroll
      for (int ct = 0; ct < 4; ct++) {
        bf16x8 bfr = *(const bf16x8*)(Wtn1 + (size_t)(ct * 16 + li) * 128 + kb);
        acc[ct] = __builtin_amdgcn_mfma_f32_16x16x32_bf16(afs[ks], bfr, acc[ct], 0, 0, 0);
      }
    }
  }
#pragma unroll
  for (int ct = 0; ct < 4; ct++) {
    float bias = nb1[ct * 16 + li];
#pragma unroll
    for (int r2 = 0; r2 < 4; r2++) {
      int nl = w * 16 + q * 4 + r2;
      sT[nl * TPITCH + ct * 16 + li] = f2b(silu_f(acc[ct][r2] + bias));
    }
  }
  // wave-private sT — no barrier

#pragma unroll
  for (int ct = 0; ct < 4; ct++) acc[ct] = zero4;
#pragma unroll
  for (int ks = 0; ks < 2; ks++) {
    int kb = ks * 32 + q * 8;
    bf16x8 af = *(const bf16x8*)(sT + nrow * TPITCH + kb);
#pragma unroll
    for (int ct = 0; ct < 4; ct++) {
      bf16x8 bfr = *(const bf16x8*)(Wtn2 + (size_t)(ct * 16 + li) * 64 + kb);
      acc[ct] = __builtin_amdgcn_mfma_f32_16x16x32_bf16(af, bfr, acc[ct], 0, 0, 0);
    }
  }
#pragma unroll
  for (int ct = 0; ct < 4; ct++) {
    float bias = nb2[ct * 16 + li];
#pragma unroll
    for (int r2 = 0; r2 < 4; r2++) {
      int node = nb + w * 16 + q * 4 + r2;
      if (node < N_NODES) {
        float nm = nmask[node];
        size_t o = (size_t)node * 64 + ct * 16 + li;
        float hv = (h[o] + acc[ct][r2] + bias) * nm;
        h[o] = hv;
        hbf[o] = f2b(hv);
      }
    }
  }
}

// ---------------- output heads ----------------
__global__ void k_hout(const float* __restrict__ h, const float* __restrict__ W,
                       const float* __restrict__ b, const float* __restrict__ nmask,
                       float* __restrict__ out) {
  int id = blockIdx.x * 256 + threadIdx.x;
  if (id >= N_NODES * 16) return;
  int n = id >> 4, j = id & 15;
  float s = b[j];
#pragma unroll
  for (int k = 0; k < 64; k++) s += h[(size_t)n * 64 + k] * W[k * 16 + j];
  out[id] = s * nmask[n];
}
// sequential ebuf read (sorted), scattered 32B write to original positions
__global__ void k_eout(const unsigned short* __restrict__ ebuf, const float* __restrict__ W,
                       const float* __restrict__ b, const float* __restrict__ emask,
                       const int* __restrict__ elist, float* __restrict__ out) {
  int id = blockIdx.x * 256 + threadIdx.x;
  if (id >= N_EDGES * 8) return;
  int pos = id >> 3, j = id & 7;
  int orig = elist[pos];
  float s = b[j];
#pragma unroll
  for (int k = 0; k < 64; k++) s += b2f(ebuf[(size_t)pos * 64 + k]) * W[k * 8 + j];
  out[(size_t)orig * 8 + j] = s * emask[orig];
}

extern "C" void kernel_launch(void* const* d_in, const int* in_sizes, int n_in,
                              void* d_out, int out_size, void* d_ws, size_t ws_size,
                              hipStream_t stream) {
  (void)in_sizes; (void)n_in; (void)out_size; (void)ws_size;
  const float* in_h   = (const float*)d_in[0];
  const float* in_x   = (const float*)d_in[1];
  const float* in_ea  = (const float*)d_in[2];
  const float* nmask  = (const float*)d_in[3];
  const float* emask  = (const float*)d_in[4];
  const float* Wn_in  = (const float*)d_in[5];
  const float* bn_in  = (const float*)d_in[6];
  const float* Wn_out = (const float*)d_in[7];
  const float* bn_out = (const float*)d_in[8];
  const float* We_in  = (const float*)d_in[9];
  const float* be_in  = (const float*)d_in[10];
  const float* We_out = (const float*)d_in[11];
  const float* be_out = (const float*)d_in[12];
  const float* eW1    = (const float*)d_in[13];
  const float* eb1    = (const float*)d_in[14];
  const float* eW2    = (const float*)d_in[15];
  const float* eb2    = (const float*)d_in[16];
  const float* nW1    = (const float*)d_in[17];
  const float* nb1    = (const float*)d_in[18];
  const float* nW2    = (const float*)d_in[19];
  const float* nb2    = (const float*)d_in[20];
  const float* cW1    = (const float*)d_in[21];
  const float* cb1    = (const float*)d_in[22];
  const float* cW2    = (const float*)d_in[23];
  const int*   eidx   = (const int*)d_in[24];

  char* ws = (char*)d_ws;
  size_t off = 0;
  auto alloc = [&](size_t bytes) {
    size_t o = off; off = (off + bytes + 255) & ~(size_t)255; return (void*)(ws + o);
  };
  float* h             = (float*)alloc((size_t)N_NODES * 64 * 4);
  unsigned short* hbf  = (unsigned short*)alloc((size_t)N_NODES * 64 * 2);
  unsigned short* ebuf = (unsigned short*)alloc((size_t)N_EDGES * 64 * 2);
  float* agg           = (float*)alloc((size_t)N_NODES * 64 * 4);
  float* xb0           = (float*)alloc((size_t)N_NODES * 3 * 4);
  float* xb1           = (float*)alloc((size_t)N_NODES * 3 * 4);
  int* cnt             = (int*)alloc((size_t)N_NODES * 4);
  int* rowptr          = (int*)alloc((size_t)(N_NODES + 1) * 4);
  int* cur             = (int*)alloc((size_t)N_NODES * 4);
  int* elist           = (int*)alloc((size_t)N_EDGES * 4);
  int* rsorted         = (int*)alloc((size_t)N_EDGES * 4);
  int* csorted         = (int*)alloc((size_t)N_EDGES * 4);
  float* msorted       = (float*)alloc((size_t)N_EDGES * 4);
  unsigned short* Wt1  = (unsigned short*)alloc((size_t)NLAYERS * 64 * K1PAD * 2);
  unsigned short* Wt2  = (unsigned short*)alloc((size_t)NLAYERS * 64 * 64 * 2);
  unsigned short* Wtc  = (unsigned short*)alloc((size_t)NLAYERS * 64 * 64 * 2);
  unsigned short* Wtn1 = (unsigned short*)alloc((size_t)NLAYERS * 64 * 128 * 2);
  unsigned short* Wtn2 = (unsigned short*)alloc((size_t)NLAYERS * 64 * 64 * 2);

  // one-time CSR build + edge sort (edge_index constant across layers)
  hipMemsetAsync(cnt, 0, (size_t)N_NODES * 4, stream);
  k_hist<<<(N_EDGES + 255) / 256, 256, 0, stream>>>(eidx, cnt);
  k_scan<<<1, 1024, 0, stream>>>(cnt, rowptr, cur);
  k_scatter<<<(N_EDGES + 255) / 256, 256, 0, stream>>>(eidx, emask, cur, elist,
                                                       rsorted, csorted, msorted);

  k_convW1<<<(NLAYERS * 64 * K1PAD + 255) / 256, 256, 0, stream>>>(eW1, Wt1);
  k_convT<<<(NLAYERS * 64 * 64 + 255) / 256, 256, 0, stream>>>(eW2, Wt2, 64);
  k_convT<<<(NLAYERS * 64 * 64 + 255) / 256, 256, 0, stream>>>(cW1, Wtc, 64);
  k_convT<<<(NLAYERS * 64 * 128 + 255) / 256, 256, 0, stream>>>(nW1, Wtn1, 128);
  k_convT<<<(NLAYERS * 64 * 64 + 255) / 256, 256, 0, stream>>>(nW2, Wtn2, 64);

  k_h0<<<(N_NODES * 64 + 255) / 256, 256, 0, stream>>>(in_h, Wn_in, bn_in, h, hbf);
  k_e0<<<(N_EDGES * 64 + 255) / 256, 256, 0, stream>>>(in_ea, We_in, be_in, elist, ebuf);
  hipMemcpyAsync(xb0, in_x, (size_t)N_NODES * 3 * 4, hipMemcpyDeviceToDevice, stream);

  for (int l = 0; l < NLAYERS; l++) {
    float* xi = (l & 1) ? xb1 : xb0;
    float* xo = (l & 1) ? xb0 : xb1;
    hipMemsetAsync(agg, 0, (size_t)N_NODES * 64 * 4, stream);
    hipMemcpyAsync(xo, xi, (size_t)N_NODES * 3 * 4, hipMemcpyDeviceToDevice, stream);
    edge_kernel<<<NTILES, 256, 0, stream>>>(
        hbf, ebuf, xi, xo, agg, rsorted, csorted, msorted,
        Wt1 + (size_t)l * 64 * K1PAD, Wt2 + (size_t)l * 64 * 64, Wtc + (size_t)l * 64 * 64,
        eb1 + l * 64, eb2 + l * 64, cb1 + l * 64, cW2 + l * 64);
    node_kernel<<<(N_NODES + 63) / 64, 256, 0, stream>>>(
        h, hbf, agg, xo, nmask,
        Wtn1 + (size_t)l * 64 * 128, Wtn2 + (size_t)l * 64 * 64, nb1 + l * 64, nb2 + l * 64);
  }

  float* out = (float*)d_out;
  k_hout<<<(N_NODES * 16 + 255) / 256, 256, 0, stream>>>(h, Wn_out, bn_out, nmask, out);
  k_eout<<<(N_EDGES * 8 + 255) / 256, 256, 0, stream>>>(ebuf, We_out, be_out, emask, elist,
                                                        out + 950000);
  hipMemcpyAsync(out + 800000, xb0, (size_t)N_NODES * 3 * 4, hipMemcpyDeviceToDevice, stream);
}